// Round 1
// baseline (423.643 us; speedup 1.0000x reference)
//
#include <hip/hip_runtime.h>

// Haar wavelet transform along seq axis:
//   x: (64, 4096, 256) fp32  ->  out: (64, 2048, 512) fp32
//   out[b, t, 2f]   = (x[b,2t,f] + x[b,2t+1,f]) * INV_SQRT2
//   out[b, t, 2f+1] = (x[b,2t,f] - x[b,2t+1,f]) * INV_SQRT2
//
// Flattened: pair index p = b*2048 + t  (p in [0, 131072))
//   row0 base = p*512, row1 base = p*512 + 256, out row base = p*512.
// Memory-bound: 256 MiB in + 256 MiB out; floor ~85 us at 6.3 TB/s.

#define INV_SQRT2 0.70710678118654752440f

__global__ __launch_bounds__(256) void W_Transform_45938970198411_kernel(
        const float* __restrict__ x, float* __restrict__ out) {
    const unsigned int i  = blockIdx.x * blockDim.x + threadIdx.x;  // [0, 8388608)
    const unsigned int f4 = i & 63u;   // which float4 chunk within a 256-float row
    const unsigned int p  = i >> 6;    // pair index

    const size_t base = (size_t)p * 512;
    const float4 a = *(const float4*)(x + base + f4 * 4);          // row 2t
    const float4 b = *(const float4*)(x + base + 256 + f4 * 4);    // row 2t+1

    float4 o0, o1;
    o0.x = (a.x + b.x) * INV_SQRT2;
    o0.y = (a.x - b.x) * INV_SQRT2;
    o0.z = (a.y + b.y) * INV_SQRT2;
    o0.w = (a.y - b.y) * INV_SQRT2;
    o1.x = (a.z + b.z) * INV_SQRT2;
    o1.y = (a.z - b.z) * INV_SQRT2;
    o1.z = (a.w + b.w) * INV_SQRT2;
    o1.w = (a.w - b.w) * INV_SQRT2;

    float4* ob = (float4*)(out + base + f4 * 8);
    ob[0] = o0;
    ob[1] = o1;
}

extern "C" void kernel_launch(void* const* d_in, const int* in_sizes, int n_in,
                              void* d_out, int out_size, void* d_ws, size_t ws_size,
                              hipStream_t stream) {
    const float* x = (const float*)d_in[0];
    float* out = (float*)d_out;
    // total threads = 64*2048*64 = 8,388,608 -> 32768 blocks of 256
    const int n_threads = 64 * 2048 * 64;
    const int block = 256;
    const int grid = n_threads / block;
    W_Transform_45938970198411_kernel<<<grid, block, 0, stream>>>(x, out);
}

// Round 2
// 421.079 us; speedup vs baseline: 1.0061x; 1.0061x over previous
//
#include <hip/hip_runtime.h>

// Haar wavelet transform along seq axis:
//   x: (64, 4096, 256) fp32  ->  out: (64, 2048, 512) fp32
//   out[b, t, 2f]   = (x[b,2t,f] + x[b,2t+1,f]) * INV_SQRT2
//   out[b, t, 2f+1] = (x[b,2t,f] - x[b,2t+1,f]) * INV_SQRT2
//
// pair index p = b*2048 + t; row0 = x + p*512, row1 = row0 + 256,
// out row = out + p*512 (512 floats).
//
// Mapping (R2): 64 lanes per out row. Lane l stores out floats [4l,4l+4)
// and [256+4l, 256+4l+4) -> each store instruction is a contiguous 1 KiB
// wave region (R1's version had 16B stores at 32B stride -> half-filled
// sectors). Inputs become four float2 loads (f=2l,2l+1 and f=128+2l,128+2l+1),
// each wave-contiguous 512 B. Memory-bound: 537 MB traffic, floor ~85 us.

#define INV_SQRT2 0.70710678118654752440f

__global__ __launch_bounds__(256) void W_Transform_45938970198411_kernel(
        const float* __restrict__ x, float* __restrict__ out) {
    const unsigned int i = blockIdx.x * blockDim.x + threadIdx.x;  // [0, 8388608)
    const unsigned int l = i & 63u;   // lane-task within one output row
    const unsigned int p = i >> 6;    // pair-row index

    const float* __restrict__ r0 = x + (size_t)p * 512;        // row 2t
    const float* __restrict__ r1 = r0 + 256;                   // row 2t+1

    const float2 a0 = *(const float2*)(r0 + 2 * l);            // f = 2l, 2l+1
    const float2 b0 = *(const float2*)(r1 + 2 * l);
    const float2 a1 = *(const float2*)(r0 + 128 + 2 * l);      // f = 128+2l, ...
    const float2 b1 = *(const float2*)(r1 + 128 + 2 * l);

    float4 o0, o1;
    o0.x = (a0.x + b0.x) * INV_SQRT2;
    o0.y = (a0.x - b0.x) * INV_SQRT2;
    o0.z = (a0.y + b0.y) * INV_SQRT2;
    o0.w = (a0.y - b0.y) * INV_SQRT2;
    o1.x = (a1.x + b1.x) * INV_SQRT2;
    o1.y = (a1.x - b1.x) * INV_SQRT2;
    o1.z = (a1.y + b1.y) * INV_SQRT2;
    o1.w = (a1.y - b1.y) * INV_SQRT2;

    float* ob = out + (size_t)p * 512;
    *(float4*)(ob + 4 * l) = o0;          // contiguous 1 KiB across the wave
    *(float4*)(ob + 256 + 4 * l) = o1;    // contiguous 1 KiB across the wave
}

extern "C" void kernel_launch(void* const* d_in, const int* in_sizes, int n_in,
                              void* d_out, int out_size, void* d_ws, size_t ws_size,
                              hipStream_t stream) {
    const float* x = (const float*)d_in[0];
    float* out = (float*)d_out;
    // total threads = 131072 rows * 64 lanes = 8,388,608 -> 32768 blocks of 256
    const int n_threads = 64 * 2048 * 64;
    const int block = 256;
    const int grid = n_threads / block;
    W_Transform_45938970198411_kernel<<<grid, block, 0, stream>>>(x, out);
}